// Round 1
// baseline (154.204 us; speedup 1.0000x reference)
//
#include <hip/hip_runtime.h>

// Upsample 2x (nearest) + horizontal 1x16 FIR (flattened 4x4 kernel), SAME pad.
// x: (32,512,512,1) fp32, kernel: 16 fp32, out: (32,1024,1024,1) fp32.
//
// Key reductions:
//  - conv is horizontal-only and upsampled rows 2r,2r+1 are identical
//    -> output rows 2r,2r+1 identical: compute once, store twice.
//  - up[p]=x[p>>1] collapses the 16-tap FIR to 9-tap (even cols) / 8-tap
//    (odd cols) polyphase filters on x; with x zero-padded by 4 each side
//    the collapsed form is exact at boundaries (every collapsed tap's
//    underlying positions are in range iff the x index is in [0,512)).

#define W_IN  512
#define H_IN  512
#define NB    32
#define W_OUT 1024

__global__ __launch_bounds__(256) void upsample_blur_kernel(
    const float* __restrict__ x,
    const float* __restrict__ kern,
    float* __restrict__ out)
{
    // LDS row: indices 0..519; data at [4..515], zero halo [0..3] and [516..519]
    __shared__ float row[520];

    const int rowIdx = blockIdx.x;          // n*512 + r
    const int n = rowIdx >> 9;
    const int r = rowIdx & 511;
    const int t = threadIdx.x;              // 0..255

    // zero halos
    if (t < 8) {
        const int idx = (t < 4) ? t : (512 + t);   // 0..3, 516..519
        row[idx] = 0.0f;
    }

    // stage input row (512 floats) into LDS at offset 4 (16B-aligned -> float2 ok)
    const float* xrow = x + (size_t)(n * H_IN + r) * W_IN;
    reinterpret_cast<float2*>(row + 4)[t] = reinterpret_cast<const float2*>(xrow)[t];

    // load flat 4x4 kernel (uniform -> scalar-cached) and build collapsed taps
    float kf[16];
#pragma unroll
    for (int i = 0; i < 16; ++i) kf[i] = kern[i];

    float we[9], wo[8];
    we[0] = kf[0];
#pragma unroll
    for (int i = 0; i < 7; ++i) we[i + 1] = kf[2 * i + 1] + kf[2 * i + 2];
    we[8] = kf[15];
#pragma unroll
    for (int i = 0; i < 8; ++i) wo[i] = kf[2 * i] + kf[2 * i + 1];

    __syncthreads();

    // thread t computes output columns w = 4t..4t+3  (u = 2t, 2t+1)
    // needs xv[2t-4 .. 2t+5] = row[2t + 0 .. 2t + 9]
    float v[10];
#pragma unroll
    for (int i = 0; i < 10; ++i) v[i] = row[2 * t + i];   // stride-2: 2-way, free

    float o0 = 0.f, o1 = 0.f, o2 = 0.f, o3 = 0.f;
#pragma unroll
    for (int j = 0; j < 9; ++j) o0 += we[j] * v[j];       // w=4t   (even, u=2t)
#pragma unroll
    for (int j = 0; j < 8; ++j) o1 += wo[j] * v[j + 1];   // w=4t+1 (odd,  u=2t)
#pragma unroll
    for (int j = 0; j < 9; ++j) o2 += we[j] * v[j + 1];   // w=4t+2 (even, u=2t+1)
#pragma unroll
    for (int j = 0; j < 8; ++j) o3 += wo[j] * v[j + 2];   // w=4t+3 (odd,  u=2t+1)

    const float4 o = make_float4(o0, o1, o2, o3);
    const size_t outRowBase = ((size_t)n * W_OUT + 2 * r) * (size_t)W_OUT;
    float4* out4a = reinterpret_cast<float4*>(out + outRowBase);
    float4* out4b = reinterpret_cast<float4*>(out + outRowBase + W_OUT);
    out4a[t] = o;   // row 2r
    out4b[t] = o;   // row 2r+1 (identical)
}

extern "C" void kernel_launch(void* const* d_in, const int* in_sizes, int n_in,
                              void* d_out, int out_size, void* d_ws, size_t ws_size,
                              hipStream_t stream) {
    const float* x    = (const float*)d_in[0];
    const float* kern = (const float*)d_in[1];
    float* out        = (float*)d_out;

    const int numRows = NB * H_IN;   // 16384 blocks, one per input row
    upsample_blur_kernel<<<numRows, 256, 0, stream>>>(x, kern, out);
}